// Round 4
// baseline (179.685 us; speedup 1.0000x reference)
//
#include <hip/hip_runtime.h>
#include <hip/hip_cooperative_groups.h>

namespace cg = cooperative_groups;

#define V   1024
#define NH  16384
#define NM  16384

#define BAND_LOW_MAX    500.0f
#define BAND_MID_MAX    2000.0f
#define ENERGY_THRESHOLD 0.5f

// clang native vector type (required by __builtin_nontemporal_*)
typedef float f32x4 __attribute__((ext_vector_type(4)));

// ---------------------------------------------------------------------------
// Fused cooperative kernel: 1024 blocks x 256 threads, 1 block per voice.
// Phase 1: load harm row into REGISTERS (16 f32x4/thread), band-reduce,
//          publish per-voice stats to ws (planar [5][V]).
// grid.sync()
// Phase 2: every block redundantly reduces the stats array -> totals.
// Phase 3: apply gains to register-held harm (no re-read), stream noise NT.
// ---------------------------------------------------------------------------
__global__ __launch_bounds__(256, 4)
void fused_all(const float* __restrict__ harm,
               const float* __restrict__ noise,
               const float* __restrict__ f0_hz,
               const float* __restrict__ cw,
               const float* __restrict__ wd,
               const int*   __restrict__ is_active,
               float* __restrict__ out,
               float* stats /* [5][V] planar in ws */) {
    const int v   = blockIdx.x;
    const int tid = threadIdx.x;
    const float f0 = f0_hz[v];

    // ---- Phase 1: load row into regs + band sums -------------------------
    const f32x4* hrow = (const f32x4*)harm + (size_t)v * 4096;
    f32x4 h[16];
    #pragma unroll
    for (int k = 0; k < 16; ++k)
        h[k] = __builtin_nontemporal_load(hrow + tid + k * 256);

    float e0 = 0.f, e1 = 0.f, e2 = 0.f;
    #pragma unroll
    for (int k = 0; k < 16; ++k) {
        const int hbase = (tid + k * 256) * 4;
        #pragma unroll
        for (int j = 0; j < 4; ++j) {
            const float freq = f0 * (float)(hbase + j + 1);  // fp32 mul, matches jnp
            const float amp  = h[k][j];
            if (freq < BAND_LOW_MAX)       e0 += amp;
            else if (freq < BAND_MID_MAX)  e1 += amp;
            else                           e2 += amp;
        }
    }
    for (int off = 32; off > 0; off >>= 1) {
        e0 += __shfl_down(e0, off);
        e1 += __shfl_down(e1, off);
        e2 += __shfl_down(e2, off);
    }
    __shared__ float s1[3][4];
    __shared__ float ebc[3];     // raw per-voice band energies (broadcast)
    const int wid  = tid >> 6;
    const int lane = tid & 63;
    if (lane == 0) { s1[0][wid] = e0; s1[1][wid] = e1; s1[2][wid] = e2; }
    __syncthreads();
    if (tid == 0) {
        const float t0 = s1[0][0] + s1[0][1] + s1[0][2] + s1[0][3];
        const float t1 = s1[1][0] + s1[1][1] + s1[1][2] + s1[1][3];
        const float t2 = s1[2][0] + s1[2][1] + s1[2][2] + s1[2][3];
        ebc[0] = t0; ebc[1] = t1; ebc[2] = t2;
        const float af = (is_active[v] != 0) ? 1.0f : 0.0f;
        stats[0 * V + v] = t0 * af;
        stats[1 * V + v] = t1 * af;
        stats[2 * V + v] = t2 * af;
        stats[3 * V + v] = cw[v] * af;
        stats[4 * V + v] = af;
    }

    cg::this_grid().sync();   // all stats visible device-wide

    // ---- Phase 2: redundant totals reduce (each block, deterministic) ---
    float r[5];
    #pragma unroll
    for (int p = 0; p < 5; ++p) {
        const f32x4 x = ((const f32x4*)(stats + p * V))[tid];  // 256 f32x4/plane
        r[p] = (x[0] + x[1]) + (x[2] + x[3]);
    }
    #pragma unroll
    for (int p = 0; p < 5; ++p)
        for (int off = 32; off > 0; off >>= 1)
            r[p] += __shfl_down(r[p], off);
    __shared__ float s2[5][4];
    if (lane == 0) {
        #pragma unroll
        for (int p = 0; p < 5; ++p) s2[p][wid] = r[p];
    }
    __syncthreads();
    const float TE0 = s2[0][0] + s2[0][1] + s2[0][2] + s2[0][3];
    const float TE1 = s2[1][0] + s2[1][1] + s2[1][2] + s2[1][3];
    const float TE2 = s2[2][0] + s2[2][1] + s2[2][2] + s2[2][3];
    const float TW  = s2[3][0] + s2[3][1] + s2[3][2] + s2[3][3];
    const float NA  = s2[4][0] + s2[4][1] + s2[4][2] + s2[4][3];

    // ---- per-voice gains (all threads, block-uniform) --------------------
    const bool  act  = (is_active[v] != 0);
    const float af   = act ? 1.0f : 0.0f;
    const bool  changed = (NA >= 1.5f);        // n_active >= 2
    const float w     = cw[v];
    const float share = (w / fmaxf(TW, 1e-6f)) * ENERGY_THRESHOLD;

    const float er[3] = { ebc[0], ebc[1], ebc[2] };
    const float TE[3] = { TE0, TE1, TE2 };

    const float tbefore = er[0] + er[1] + er[2];
    float tafter = 0.f;
    float g[3];
    #pragma unroll
    for (int b = 0; b < 3; ++b) {
        const float ea     = er[b] * af;
        const float excess = ea - share;
        const float exr    = excess / fmaxf(ea, 1e-6f);
        const float red    = fmaxf(0.3f, 1.0f - wd[v * 3 + b] * exr * 0.5f);
        const bool apply   = (TE[b] > ENERGY_THRESHOLD) && (ea > 0.0f) &&
                             (excess > 0.0f) && act;
        const float gb = apply ? red : 1.0f;
        tafter += gb * er[b];
        g[b] = changed ? gb : 1.0f;
    }
    const float nscale = (tbefore > 1e-6f) ? (tafter / tbefore) : 1.0f;
    const float nse    = (changed && act) ? nscale : 1.0f;
    const float g0 = g[0], g1 = g[1], g2 = g[2];

    // ---- Phase 3: apply to register-held harm, then stream noise ---------
    f32x4* orow = (f32x4*)out + (size_t)v * 8192;
    #pragma unroll
    for (int k = 0; k < 16; ++k) {
        const int hbase = (tid + k * 256) * 4;
        f32x4 o;
        #pragma unroll
        for (int j = 0; j < 4; ++j) {
            const float freq = f0 * (float)(hbase + j + 1);
            const float gg = (freq < BAND_LOW_MAX) ? g0
                           : (freq < BAND_MID_MAX) ? g1 : g2;
            o[j] = h[k][j] * gg;
        }
        __builtin_nontemporal_store(o, orow + tid + k * 256);
    }
    const f32x4* nrow = (const f32x4*)noise + (size_t)v * 4096;
    #pragma unroll
    for (int k = 0; k < 16; ++k) {
        const f32x4 n = __builtin_nontemporal_load(nrow + tid + k * 256);
        __builtin_nontemporal_store(n * nse, orow + 4096 + tid + k * 256);
    }
}

// ---------------------------------------------------------------------------
// Fallback path (proven 3-kernel structure from R1) in case the cooperative
// launch is rejected at capture time.
// ---------------------------------------------------------------------------
__global__ __launch_bounds__(256)
void pass1_band_energy(const float* __restrict__ harm,
                       const float* __restrict__ f0_hz,
                       float* __restrict__ Eraw) {
    const int v = blockIdx.x;
    const float f0 = f0_hz[v];
    const f32x4* h4 = (const f32x4*)(harm + (size_t)v * NH);
    float e0 = 0.f, e1 = 0.f, e2 = 0.f;
    for (int c = threadIdx.x; c < NH / 4; c += 256) {
        f32x4 a = h4[c];
        const int hbase = c * 4;
        #pragma unroll
        for (int j = 0; j < 4; ++j) {
            float freq = f0 * (float)(hbase + j + 1);
            if (freq < BAND_LOW_MAX)       e0 += a[j];
            else if (freq < BAND_MID_MAX)  e1 += a[j];
            else                           e2 += a[j];
        }
    }
    for (int off = 32; off > 0; off >>= 1) {
        e0 += __shfl_down(e0, off);
        e1 += __shfl_down(e1, off);
        e2 += __shfl_down(e2, off);
    }
    __shared__ float s[3][4];
    const int wid = threadIdx.x >> 6, lane = threadIdx.x & 63;
    if (lane == 0) { s[0][wid] = e0; s[1][wid] = e1; s[2][wid] = e2; }
    __syncthreads();
    if (threadIdx.x == 0) {
        Eraw[v * 3 + 0] = s[0][0] + s[0][1] + s[0][2] + s[0][3];
        Eraw[v * 3 + 1] = s[1][0] + s[1][1] + s[1][2] + s[1][3];
        Eraw[v * 3 + 2] = s[2][0] + s[2][1] + s[2][2] + s[2][3];
    }
}

__global__ __launch_bounds__(1024)
void pass2_gains(const float* __restrict__ Eraw,
                 const float* __restrict__ cw,
                 const float* __restrict__ wd,
                 const int*   __restrict__ is_active,
                 float* __restrict__ gains) {
    const int v = threadIdx.x;
    const float e0 = Eraw[v * 3 + 0], e1 = Eraw[v * 3 + 1], e2 = Eraw[v * 3 + 2];
    const bool act = (is_active[v] != 0);
    const float actf = act ? 1.0f : 0.0f;
    const float w = cw[v];
    const float ea0 = e0 * actf, ea1 = e1 * actf, ea2 = e2 * actf;
    float r0 = ea0, r1 = ea1, r2 = ea2, r3 = w * actf, r4 = actf;
    for (int off = 32; off > 0; off >>= 1) {
        r0 += __shfl_down(r0, off); r1 += __shfl_down(r1, off);
        r2 += __shfl_down(r2, off); r3 += __shfl_down(r3, off);
        r4 += __shfl_down(r4, off);
    }
    __shared__ float s[5][16];
    __shared__ float tot[5];
    const int wid = threadIdx.x >> 6, lane = threadIdx.x & 63;
    if (lane == 0) { s[0][wid]=r0; s[1][wid]=r1; s[2][wid]=r2; s[3][wid]=r3; s[4][wid]=r4; }
    __syncthreads();
    if (threadIdx.x < 5) {
        float t = 0.f;
        #pragma unroll
        for (int i = 0; i < 16; ++i) t += s[threadIdx.x][i];
        tot[threadIdx.x] = t;
    }
    __syncthreads();
    const float TE[3] = { tot[0], tot[1], tot[2] };
    const float TW = tot[3];
    const bool changed = (tot[4] >= 1.5f);
    const float share = (w / fmaxf(TW, 1e-6f)) * ENERGY_THRESHOLD;
    const float ea[3] = { ea0, ea1, ea2 };
    const float er[3] = { e0, e1, e2 };
    const float tbefore = e0 + e1 + e2;
    float tafter = 0.f;
    float g[3];
    #pragma unroll
    for (int b = 0; b < 3; ++b) {
        const float excess = ea[b] - share;
        const float exr = excess / fmaxf(ea[b], 1e-6f);
        const float red = fmaxf(0.3f, 1.0f - wd[v * 3 + b] * exr * 0.5f);
        const bool apply = (TE[b] > ENERGY_THRESHOLD) && (ea[b] > 0.0f) &&
                           (excess > 0.0f) && act;
        const float gb = apply ? red : 1.0f;
        tafter += gb * er[b];
        g[b] = changed ? gb : 1.0f;
    }
    const float nscale = (tbefore > 1e-6f) ? (tafter / tbefore) : 1.0f;
    gains[v * 4 + 0] = g[0];
    gains[v * 4 + 1] = g[1];
    gains[v * 4 + 2] = g[2];
    gains[v * 4 + 3] = (changed && act) ? nscale : 1.0f;
}

__global__ __launch_bounds__(256)
void pass3_apply(const float* __restrict__ harm,
                 const float* __restrict__ noise,
                 const float* __restrict__ f0_hz,
                 const float* __restrict__ gains,
                 float* __restrict__ out) {
    const int v   = blockIdx.x >> 4;
    const int seg = (blockIdx.x & 15) << 9;
    const int c0  = seg + threadIdx.x;
    f32x4* outrow = (f32x4*)out + (size_t)v * 8192;
    if (seg < 4096) {
        const float f0 = f0_hz[v];
        const float g0 = gains[v*4+0], g1 = gains[v*4+1], g2 = gains[v*4+2];
        const f32x4* hrow = (const f32x4*)harm + (size_t)v * 4096;
        const f32x4 a0 = hrow[c0];
        const f32x4 a1 = hrow[c0 + 256];
        f32x4 o0, o1;
        #pragma unroll
        for (int j = 0; j < 4; ++j) {
            const float fr0 = f0 * (float)(c0 * 4 + j + 1);
            const float fr1 = f0 * (float)((c0 + 256) * 4 + j + 1);
            o0[j] = a0[j] * ((fr0 < BAND_LOW_MAX) ? g0 : (fr0 < BAND_MID_MAX) ? g1 : g2);
            o1[j] = a1[j] * ((fr1 < BAND_LOW_MAX) ? g0 : (fr1 < BAND_MID_MAX) ? g1 : g2);
        }
        __builtin_nontemporal_store(o0, outrow + c0);
        __builtin_nontemporal_store(o1, outrow + c0 + 256);
    } else {
        const float ns = gains[v * 4 + 3];
        const f32x4* nrow = (const f32x4*)noise + (size_t)v * 4096 - 4096;
        const f32x4 n0 = __builtin_nontemporal_load(nrow + c0);
        const f32x4 n1 = __builtin_nontemporal_load(nrow + c0 + 256);
        __builtin_nontemporal_store(n0 * ns, outrow + c0);
        __builtin_nontemporal_store(n1 * ns, outrow + c0 + 256);
    }
}

// ---------------------------------------------------------------------------
extern "C" void kernel_launch(void* const* d_in, const int* in_sizes, int n_in,
                              void* d_out, int out_size, void* d_ws, size_t ws_size,
                              hipStream_t stream) {
    const float* harm  = (const float*)d_in[0];
    const float* noise = (const float*)d_in[1];
    const float* f0    = (const float*)d_in[2];
    const float* cw    = (const float*)d_in[3];
    const float* wd    = (const float*)d_in[4];
    const int*   act   = (const int*)d_in[5];
    float* out   = (float*)d_out;
    float* stats = (float*)d_ws;   // 5*V floats

    void* args[] = { (void*)&harm, (void*)&noise, (void*)&f0, (void*)&cw,
                     (void*)&wd, (void*)&act, (void*)&out, (void*)&stats };
    hipError_t err = hipLaunchCooperativeKernel((const void*)fused_all,
                                                dim3(V), dim3(256),
                                                args, 0, stream);
    if (err != hipSuccess) {
        // fallback: proven 3-kernel path
        float* Eraw  = (float*)d_ws;
        float* gains = Eraw + 4096;
        pass1_band_energy<<<V, 256, 0, stream>>>(harm, f0, Eraw);
        pass2_gains<<<1, 1024, 0, stream>>>(Eraw, cw, wd, act, gains);
        pass3_apply<<<V * 16, 256, 0, stream>>>(harm, noise, f0, gains, out);
    }
}

// Round 5
// 56.887 us; speedup vs baseline: 3.1586x; 3.1586x over previous
//
#include <hip/hip_runtime.h>

#define V   1024
#define NH  16384
#define NM  16384

#define BAND_LOW_MAX    500.0f
#define BAND_MID_MAX    2000.0f
#define ENERGY_THRESHOLD 0.5f

// clang native vector type (required by __builtin_nontemporal_*)
typedef float f32x4 __attribute__((ext_vector_type(4)));

// ---------------------------------------------------------------------------
// Kernel 1: per-voice band stats. One block per voice.
// stats planar [5][V]: {E_low*af, E_mid*af, E_high*af, cw*af, af}
// Regular caching loads: harm should stay L3-resident for kernel 2's re-read.
// ---------------------------------------------------------------------------
__global__ __launch_bounds__(256)
void k1_stats(const float* __restrict__ harm,
              const float* __restrict__ f0_hz,
              const float* __restrict__ cw,
              const int*   __restrict__ is_active,
              float* __restrict__ stats /* [5][V] */) {
    const int v   = blockIdx.x;
    const int tid = threadIdx.x;
    const float f0 = f0_hz[v];
    const f32x4* hrow = (const f32x4*)harm + (size_t)v * 4096;

    float e0 = 0.f, e1 = 0.f, e2 = 0.f;
    #pragma unroll
    for (int k = 0; k < 16; ++k) {
        const f32x4 a = hrow[tid + k * 256];
        const int hbase = (tid + k * 256) * 4;
        #pragma unroll
        for (int j = 0; j < 4; ++j) {
            const float freq = f0 * (float)(hbase + j + 1);  // fp32 mul, matches jnp
            if (freq < BAND_LOW_MAX)       e0 += a[j];
            else if (freq < BAND_MID_MAX)  e1 += a[j];
            else                           e2 += a[j];
        }
    }
    for (int off = 32; off > 0; off >>= 1) {
        e0 += __shfl_down(e0, off);
        e1 += __shfl_down(e1, off);
        e2 += __shfl_down(e2, off);
    }
    __shared__ float s[3][4];
    const int wid  = tid >> 6;
    const int lane = tid & 63;
    if (lane == 0) { s[0][wid] = e0; s[1][wid] = e1; s[2][wid] = e2; }
    __syncthreads();
    if (tid == 0) {
        const float t0 = s[0][0] + s[0][1] + s[0][2] + s[0][3];
        const float t1 = s[1][0] + s[1][1] + s[1][2] + s[1][3];
        const float t2 = s[2][0] + s[2][1] + s[2][2] + s[2][3];
        const float af = (is_active[v] != 0) ? 1.0f : 0.0f;
        stats[0 * V + v] = t0 * af;
        stats[1 * V + v] = t1 * af;
        stats[2 * V + v] = t2 * af;
        stats[3 * V + v] = cw[v] * af;
        stats[4 * V + v] = af;
    }
}

// ---------------------------------------------------------------------------
// Kernel 2: fused totals-reduce + gains + elementwise apply.
// Grid = V*8 blocks of 256. Each block:
//  (a) redundantly reduces the [5][V] stats (deterministic fixed tree;
//      identical values in every block -> identical results),
//  (b) computes its voice's gains (block-uniform),
//  (c) streams 1024 f32x4: parts 0-3 = harm quarter-rows, 4-7 = noise.
// NT stores only (out never re-read); caching loads for harm/noise.
// ---------------------------------------------------------------------------
__global__ __launch_bounds__(256)
void k2_apply(const float* __restrict__ harm,
              const float* __restrict__ noise,
              const float* __restrict__ f0_hz,
              const float* __restrict__ cw,
              const float* __restrict__ wd,
              const int*   __restrict__ is_active,
              const float* __restrict__ stats,
              float* __restrict__ out) {
    const int bid  = blockIdx.x;
    const int v    = bid >> 3;
    const int part = bid & 7;
    const int tid  = threadIdx.x;

    // ---- (a) totals over stats: plane p is 1024 floats = 256 f32x4 -------
    const f32x4* sp = (const f32x4*)stats;
    const f32x4 x0 = sp[0 * 256 + tid];
    const f32x4 x1 = sp[1 * 256 + tid];
    const f32x4 x2 = sp[2 * 256 + tid];
    const f32x4 x3 = sp[3 * 256 + tid];
    const f32x4 x4 = sp[4 * 256 + tid];
    float r0 = (x0[0] + x0[1]) + (x0[2] + x0[3]);
    float r1 = (x1[0] + x1[1]) + (x1[2] + x1[3]);
    float r2 = (x2[0] + x2[1]) + (x2[2] + x2[3]);
    float r3 = (x3[0] + x3[1]) + (x3[2] + x3[3]);
    float r4 = (x4[0] + x4[1]) + (x4[2] + x4[3]);
    for (int off = 32; off > 0; off >>= 1) {
        r0 += __shfl_down(r0, off);
        r1 += __shfl_down(r1, off);
        r2 += __shfl_down(r2, off);
        r3 += __shfl_down(r3, off);
        r4 += __shfl_down(r4, off);
    }
    __shared__ float s2[5][4];
    const int wid  = tid >> 6;
    const int lane = tid & 63;
    if (lane == 0) {
        s2[0][wid] = r0; s2[1][wid] = r1; s2[2][wid] = r2;
        s2[3][wid] = r3; s2[4][wid] = r4;
    }
    __syncthreads();
    const float TE[3] = {
        s2[0][0] + s2[0][1] + s2[0][2] + s2[0][3],
        s2[1][0] + s2[1][1] + s2[1][2] + s2[1][3],
        s2[2][0] + s2[2][1] + s2[2][2] + s2[2][3] };
    const float TW = s2[3][0] + s2[3][1] + s2[3][2] + s2[3][3];
    const float NA = s2[4][0] + s2[4][1] + s2[4][2] + s2[4][3];

    // ---- (b) per-voice gains (block-uniform scalar loads) -----------------
    const bool  act     = (is_active[v] != 0);
    const bool  changed = (NA >= 1.5f);               // n_active >= 2
    const float w       = cw[v];
    const float share   = (w / fmaxf(TW, 1e-6f)) * ENERGY_THRESHOLD;

    // ea[b] = stats plane value (already actf-scaled). For active voices
    // ea == raw energy; for inactive nse is forced to 1 so raw not needed.
    const float ea[3] = { stats[0 * V + v], stats[1 * V + v], stats[2 * V + v] };

    const float tbefore = ea[0] + ea[1] + ea[2];
    float tafter = 0.f;
    float g[3];
    #pragma unroll
    for (int b = 0; b < 3; ++b) {
        const float excess = ea[b] - share;
        const float exr    = excess / fmaxf(ea[b], 1e-6f);
        const float red    = fmaxf(0.3f, 1.0f - wd[v * 3 + b] * exr * 0.5f);
        const bool apply   = (TE[b] > ENERGY_THRESHOLD) && (ea[b] > 0.0f) &&
                             (excess > 0.0f) && act;
        const float gb = apply ? red : 1.0f;
        tafter += gb * ea[b];
        g[b] = changed ? gb : 1.0f;
    }
    const float nscale = (tbefore > 1e-6f) ? (tafter / tbefore) : 1.0f;
    const float nse    = (changed && act) ? nscale : 1.0f;
    const float g0 = g[0], g1 = g[1], g2 = g[2];

    // ---- (c) stream 1024 f32x4 (4 per thread) ----------------------------
    f32x4* orow = (f32x4*)out + (size_t)v * 8192;
    if (part < 4) {
        const float f0 = f0_hz[v];
        const f32x4* hrow = (const f32x4*)harm + (size_t)v * 4096;
        const int c0 = part * 1024 + tid;
        #pragma unroll
        for (int k = 0; k < 4; ++k) {
            const int c = c0 + k * 256;
            const f32x4 a = hrow[c];
            f32x4 o;
            #pragma unroll
            for (int j = 0; j < 4; ++j) {
                const float freq = f0 * (float)(c * 4 + j + 1);
                const float gg = (freq < BAND_LOW_MAX) ? g0
                               : (freq < BAND_MID_MAX) ? g1 : g2;
                o[j] = a[j] * gg;
            }
            __builtin_nontemporal_store(o, orow + c);
        }
    } else {
        const f32x4* nrow = (const f32x4*)noise + (size_t)v * 4096;
        const int c0 = (part - 4) * 1024 + tid;
        #pragma unroll
        for (int k = 0; k < 4; ++k) {
            const int c = c0 + k * 256;
            const f32x4 n = nrow[c];
            __builtin_nontemporal_store(n * nse, orow + 4096 + c);
        }
    }
}

// ---------------------------------------------------------------------------
extern "C" void kernel_launch(void* const* d_in, const int* in_sizes, int n_in,
                              void* d_out, int out_size, void* d_ws, size_t ws_size,
                              hipStream_t stream) {
    const float* harm  = (const float*)d_in[0];
    const float* noise = (const float*)d_in[1];
    const float* f0    = (const float*)d_in[2];
    const float* cw    = (const float*)d_in[3];
    const float* wd    = (const float*)d_in[4];
    const int*   act   = (const int*)d_in[5];
    float* out   = (float*)d_out;
    float* stats = (float*)d_ws;   // 5*V floats

    k1_stats<<<V, 256, 0, stream>>>(harm, f0, cw, act, stats);
    k2_apply<<<V * 8, 256, 0, stream>>>(harm, noise, f0, cw, wd, act, stats, out);
}